// Round 13
// baseline (2513.145 us; speedup 1.0000x reference)
//
#include <hip/hip_runtime.h>

#define N_NODES 100000
#define N_EDGES 1600000
#define ETOT    1700000   // edges + self loops
#define IN_CH   128
#define C1      256       // HEADS*HID
#define HID     64
#define BN_EPS  1e-5f
#define SLOPE   0.2f
#define NCHUNK  98        // ceil(N/1024)
#define DEG_PH  8
#define DEG_PHN 12500     // N_NODES / DEG_PH
#define FILL_PH 12
#define FILL_PHN 8334     // ceil(N_NODES / FILL_PH)

typedef __attribute__((ext_vector_type(8))) short s16x8;
typedef __attribute__((ext_vector_type(4))) float f32x4;
#define MFMA16(a, b, c) __builtin_amdgcn_mfma_f32_16x16x32_bf16(a, b, c, 0, 0, 0)

__device__ __forceinline__ float leaky(float x) { return fmaxf(x, SLOPE * x); }
__device__ __forceinline__ float elu_f(float x) { return x > 0.f ? x : __expf(x) - 1.f; }
__device__ __forceinline__ unsigned short f2bf(float f) {   // RNE fp32->bf16
  unsigned int b = __float_as_uint(f);
  return (unsigned short)((b + 0x7FFFu + ((b >> 16) & 1u)) >> 16);
}
__device__ __forceinline__ float bf2f(unsigned short u) {
  return __uint_as_float((unsigned int)u << 16);
}
// monotone float<->uint encode for atomicMax on possibly-negative floats
__device__ __forceinline__ unsigned int encf(float f) {
  unsigned int b = __float_as_uint(f);
  return b ^ ((((int)b >> 31)) | 0x80000000u);
}
__device__ __forceinline__ float decf(unsigned int k) {
  unsigned int b = (k & 0x80000000u) ? (k ^ 0x80000000u) : ~k;
  return __uint_as_float(b);
}

// ---------------- combined init: weights transpose + deg=1 + pool partials + completion ctrs ----------------
__global__ void __launch_bounds__(256) k_prep_init(const float* __restrict__ W1, const float* __restrict__ W2,
                                                   unsigned short* __restrict__ W1T, unsigned short* __restrict__ W2T,
                                                   int* __restrict__ deg, float* __restrict__ psum,
                                                   unsigned int* __restrict__ pmaxenc, unsigned int* __restrict__ ctr) {
  int i = blockIdx.x * 256 + threadIdx.x;
  if (i < N_NODES) deg[i] = 1;  // self loop
  if (i < IN_CH * C1) {
    int k = i >> 8, c = i & 255;
    W1T[c * IN_CH + k] = f2bf(W1[i]);
  }
  if (i < C1 * HID) {
    int k = i >> 6, c = i & 63;
    W2T[c * C1 + k] = f2bf(W2[i]);
  }
  if (i < 256 * 64) { psum[i] = 0.f; pmaxenc[i] = 0u; }
  if (i < 8) ctr[i] = 0u;
}

// dst-range phased degree count: confine atomic targets to 50KB (L2-resident).
__global__ void __launch_bounds__(256) k_deg_ph(const int* __restrict__ edge, int* __restrict__ deg) {
  int bpp = (N_EDGES + 1023) >> 10;      // blocks per phase, 4 edges/thread
  int ph = blockIdx.x / bpp;
  int lo = ph * DEG_PHN, hi = lo + DEG_PHN;
  int i0 = (blockIdx.x % bpp) * 1024 + threadIdx.x * 4;
  if (i0 >= N_EDGES) return;
  if (i0 + 3 < N_EDGES) {
    int4 dv = *(const int4*)(edge + N_EDGES + i0);
    if (dv.x >= lo && dv.x < hi) atomicAdd(&deg[dv.x], 1);
    if (dv.y >= lo && dv.y < hi) atomicAdd(&deg[dv.y], 1);
    if (dv.z >= lo && dv.z < hi) atomicAdd(&deg[dv.z], 1);
    if (dv.w >= lo && dv.w < hi) atomicAdd(&deg[dv.w], 1);
  } else {
    for (int j = 0; j < 4 && i0 + j < N_EDGES; j++) {
      int d = edge[N_EDGES + i0 + j];
      if (d >= lo && d < hi) atomicAdd(&deg[d], 1);
    }
  }
}

// fused partial-sum + top-scan: last-finished block performs the 98-element serial scan.
__global__ void __launch_bounds__(256) k_scan_part_top(const int* __restrict__ deg, int* __restrict__ part,
                                                       int* __restrict__ row_ptr, unsigned int* __restrict__ ctr) {
  __shared__ int ls[256];
  __shared__ unsigned int ticket;
  int t = threadIdx.x;
  int base = blockIdx.x * 1024 + t * 4;
  int s = 0;
#pragma unroll
  for (int j = 0; j < 4; j++) if (base + j < N_NODES) s += deg[base + j];
  ls[t] = s;
  __syncthreads();
  for (int off = 128; off >= 1; off >>= 1) {
    if (t < off) ls[t] += ls[t + off];
    __syncthreads();
  }
  if (t == 0) {
    __hip_atomic_store(&part[blockIdx.x], ls[0], __ATOMIC_RELEASE, __HIP_MEMORY_SCOPE_AGENT);
    ticket = atomicAdd(&ctr[0], 1u);
  }
  __syncthreads();
  if (ticket == NCHUNK - 1 && t == 0) {
    int run = 0;
    for (int i = 0; i < NCHUNK; i++) {
      int v = __hip_atomic_load(&part[i], __ATOMIC_ACQUIRE, __HIP_MEMORY_SCOPE_AGENT);
      part[i] = run;            // consumed by next kernel (launch boundary flush)
      run += v;
    }
    row_ptr[N_NODES] = run;     // == ETOT
  }
}

__global__ void __launch_bounds__(256) k_scan_down(const int* __restrict__ deg, const int* __restrict__ part,
                                                   int* __restrict__ row_ptr, int* __restrict__ cursor) {
  __shared__ int ls[256];
  int t = threadIdx.x;
  int base = blockIdx.x * 1024 + t * 4;
  int v[4];
#pragma unroll
  for (int j = 0; j < 4; j++) v[j] = (base + j < N_NODES) ? deg[base + j] : 0;
  int tsum = v[0] + v[1] + v[2] + v[3];
  ls[t] = tsum;
  __syncthreads();
  for (int off = 1; off < 256; off <<= 1) {
    int add = (t >= off) ? ls[t - off] : 0;
    __syncthreads();
    ls[t] += add;
    __syncthreads();
  }
  int excl = ls[t] - tsum + part[blockIdx.x];
#pragma unroll
  for (int j = 0; j < 4; j++) {
    int idx = base + j;
    if (idx < N_NODES) { row_ptr[idx] = excl; cursor[idx] = excl; }
    excl += v[j];
  }
}

// dst-range phased fill + layer-1 edge-weight precompute.
// Scatter window per phase: col ~570KB + w1 ~2.3MB < 4MB per-XCD L2.
__global__ void __launch_bounds__(256) k_fill_ph(const int* __restrict__ edge, int* __restrict__ cursor,
                                                 const float* __restrict__ aS, const float* __restrict__ aD,
                                                 int* __restrict__ col, float* __restrict__ w1) {
  int bpp = (ETOT + 255) >> 8;           // blocks per phase
  int ph = blockIdx.x / bpp;
  int lo = ph * FILL_PHN, hi = lo + FILL_PHN;
  int i = (blockIdx.x % bpp) * 256 + threadIdx.x;
  if (i >= ETOT) return;
  int d = (i < N_EDGES) ? edge[N_EDGES + i] : (i - N_EDGES);
  if (d < lo || d >= hi) return;         // out-of-window lanes issue nothing below
  int s = (i < N_EDGES) ? edge[i] : d;
  int pos = atomicAdd(&cursor[d], 1);
  col[pos] = s;
  float4 as4 = *(const float4*)(aS + (size_t)s * 4);
  float4 ad4 = *(const float4*)(aD + (size_t)d * 4);
  float4 w;
  w.x = __expf(fminf(leaky(as4.x + ad4.x), 80.f));
  w.y = __expf(fminf(leaky(as4.y + ad4.y), 80.f));
  w.z = __expf(fminf(leaky(as4.z + ad4.z), 80.f));
  w.w = __expf(fminf(leaky(as4.w + ad4.w), 80.f));
  *(float4*)(w1 + (size_t)pos * 4) = w;
}

// ---------------- GEMM1 (MFMA bf16): h1 = x @ W1, fused att dots ----------------
__global__ void __launch_bounds__(256) k_gemm1(const float* __restrict__ x, const unsigned short* __restrict__ W1T,
                                               const float* __restrict__ attS, const float* __restrict__ attD,
                                               unsigned short* __restrict__ h1b, float* __restrict__ aS,
                                               float* __restrict__ aD) {
  __shared__ unsigned short As[64][IN_CH + 8];   // +8 pad -> <=2-way bank conflict on frag reads
  int tid = threadIdx.x;
  int w = tid >> 6, lane = tid & 63;
  int l15 = lane & 15, l4 = lane >> 4;
  int row0 = blockIdx.x * 64;
#pragma unroll
  for (int it = 0; it < 8; it++) {
    int idx = tid + it * 256;          // float4 chunk id, 2048 total
    int r = idx >> 5;
    int k4 = (idx & 31) * 4;
    int gr = row0 + r; if (gr >= N_NODES) gr = N_NODES - 1;
    float4 v = *(const float4*)(x + (size_t)gr * IN_CH + k4);
    ushort4 bvec;
    bvec.x = f2bf(v.x); bvec.y = f2bf(v.y); bvec.z = f2bf(v.z); bvec.w = f2bf(v.w);
    *(ushort4*)&As[r][k4] = bvec;
  }
  __syncthreads();
  f32x4 acc[4][4];                     // [mf][cf]
#pragma unroll
  for (int mf = 0; mf < 4; mf++)
#pragma unroll
    for (int cf = 0; cf < 4; cf++) acc[mf][cf] = (f32x4){0.f, 0.f, 0.f, 0.f};
#pragma unroll
  for (int ks = 0; ks < 4; ks++) {
    int koff = ks * 32 + l4 * 8;
    s16x8 a[4];
#pragma unroll
    for (int mf = 0; mf < 4; mf++) a[mf] = *(const s16x8*)&As[mf * 16 + l15][koff];
#pragma unroll
    for (int cf = 0; cf < 4; cf++) {
      s16x8 b = *(const s16x8*)(W1T + (size_t)(w * 64 + cf * 16 + l15) * IN_CH + koff);
#pragma unroll
      for (int mf = 0; mf < 4; mf++) acc[mf][cf] = MFMA16(a[mf], b, acc[mf][cf]);
    }
  }
  float as_c[4], ad_c[4];
#pragma unroll
  for (int cf = 0; cf < 4; cf++) {
    as_c[cf] = attS[w * HID + cf * 16 + l15];
    ad_c[cf] = attD[w * HID + cf * 16 + l15];
  }
#pragma unroll
  for (int mf = 0; mf < 4; mf++) {
#pragma unroll
    for (int reg = 0; reg < 4; reg++) {
      int gr = row0 + mf * 16 + l4 * 4 + reg;
      bool ok = gr < N_NODES;
      float s = 0.f, dd = 0.f;
#pragma unroll
      for (int cf = 0; cf < 4; cf++) {
        float v = acc[mf][cf][reg];
        if (ok) h1b[(size_t)gr * C1 + w * 64 + cf * 16 + l15] = f2bf(v);
        s += v * as_c[cf];
        dd += v * ad_c[cf];
      }
#pragma unroll
      for (int m = 1; m <= 8; m <<= 1) { s += __shfl_xor(s, m, 64); dd += __shfl_xor(dd, m, 64); }
      if (ok && l15 == 0) {
        aS[(size_t)gr * 4 + w] = s;
        aD[(size_t)gr * 4 + w] = dd;
      }
    }
  }
}

// ---------------- layer-1 aggregate: precomputed weights, masked-tail 8-deep pipeline (round-10 best) ----------------
__global__ void __launch_bounds__(256) k_agg1(const int* __restrict__ row_ptr, const int* __restrict__ col,
                                              const float* __restrict__ w1,
                                              const unsigned short* __restrict__ h1b, const float* __restrict__ b1,
                                              const float* __restrict__ g1, const float* __restrict__ be1,
                                              const float* __restrict__ m1, const float* __restrict__ v1,
                                              unsigned short* __restrict__ hmb) {
  int wave = threadIdx.x >> 6;
  int lane = threadIdx.x & 63;
  int d = blockIdx.x * 4 + wave;
  if (d >= N_NODES) return;
  int head = lane >> 4;
  int s0 = row_ptr[d], s1 = row_ptr[d + 1];
  int s1m1 = s1 - 1;
  float denom = 0.f;
  float4 acc = {0.f, 0.f, 0.f, 0.f};
  int c0 = lane * 4;
  for (int base = s0; base < s1; base += 8) {
    int left = s1 - base;                       // wave-uniform
    int idx = base + (lane & 7); if (idx > s1m1) idx = s1m1;
    int cv = col[idx];
    int sid[8];
#pragma unroll
    for (int j = 0; j < 8; j++) sid[j] = __builtin_amdgcn_readfirstlane(__shfl(cv, j));
    float wv[8];
#pragma unroll
    for (int j = 0; j < 8; j++) {
      int wi = base + j; if (wi > s1m1) wi = s1m1;
      float wl = w1[(size_t)wi * 4 + head];
      wv[j] = (j < left) ? wl : 0.f;            // uniform mask -> cndmask, no divergence
    }
    ushort4 h[8];
#pragma unroll
    for (int j = 0; j < 8; j++) h[j] = *(const ushort4*)(h1b + ((size_t)sid[j] << 8) + c0);
#pragma unroll
    for (int j = 0; j < 8; j++) {
      denom += wv[j];
      acc.x += wv[j] * bf2f(h[j].x);
      acc.y += wv[j] * bf2f(h[j].y);
      acc.z += wv[j] * bf2f(h[j].z);
      acc.w += wv[j] * bf2f(h[j].w);
    }
  }
  float inv = 1.f / (denom + 1e-16f);
  float4 bb = *(const float4*)(b1 + c0);
  float4 gg = *(const float4*)(g1 + c0);
  float4 be = *(const float4*)(be1 + c0);
  float4 mm = *(const float4*)(m1 + c0);
  float4 vv = *(const float4*)(v1 + c0);
  ushort4 o;
  o.x = f2bf(elu_f((acc.x * inv + bb.x - mm.x) * rsqrtf(vv.x + BN_EPS) * gg.x + be.x));
  o.y = f2bf(elu_f((acc.y * inv + bb.y - mm.y) * rsqrtf(vv.y + BN_EPS) * gg.y + be.y));
  o.z = f2bf(elu_f((acc.z * inv + bb.z - mm.z) * rsqrtf(vv.z + BN_EPS) * gg.z + be.z));
  o.w = f2bf(elu_f((acc.w * inv + bb.w - mm.w) * rsqrtf(vv.w + BN_EPS) * gg.w + be.w));
  *(ushort4*)(hmb + (size_t)d * C1 + c0) = o;
}

// ---------------- GEMM2 (MFMA bf16): h2 = hm @ W2, fused att dots ----------------
__global__ void __launch_bounds__(256) k_gemm2(const unsigned short* __restrict__ hmb, const unsigned short* __restrict__ W2T,
                                               const float* __restrict__ attS, const float* __restrict__ attD,
                                               unsigned short* __restrict__ h2b, float* __restrict__ aS,
                                               float* __restrict__ aD) {
  __shared__ unsigned short As[64][C1 + 8];     // 33.8 KB
  int tid = threadIdx.x;
  int w = tid >> 6, lane = tid & 63;
  int l15 = lane & 15, l4 = lane >> 4;
  int row0 = blockIdx.x * 64;
#pragma unroll
  for (int it = 0; it < 8; it++) {
    int idx = tid + it * 256;          // uint4 chunk (8 bf16), 2048 total
    int r = idx >> 5;
    int k8 = (idx & 31) * 8;
    int gr = row0 + r; if (gr >= N_NODES) gr = N_NODES - 1;
    *(uint4*)&As[r][k8] = *(const uint4*)(hmb + (size_t)gr * C1 + k8);
  }
  __syncthreads();
  f32x4 acc[4];                        // [cf]
#pragma unroll
  for (int cf = 0; cf < 4; cf++) acc[cf] = (f32x4){0.f, 0.f, 0.f, 0.f};
#pragma unroll
  for (int ks = 0; ks < 8; ks++) {
    int koff = ks * 32 + l4 * 8;
    s16x8 a = *(const s16x8*)&As[w * 16 + l15][koff];
#pragma unroll
    for (int cf = 0; cf < 4; cf++) {
      s16x8 b = *(const s16x8*)(W2T + (size_t)(cf * 16 + l15) * C1 + koff);
      acc[cf] = MFMA16(a, b, acc[cf]);
    }
  }
  float as_c[4], ad_c[4];
#pragma unroll
  for (int cf = 0; cf < 4; cf++) {
    as_c[cf] = attS[cf * 16 + l15];
    ad_c[cf] = attD[cf * 16 + l15];
  }
#pragma unroll
  for (int reg = 0; reg < 4; reg++) {
    int gr = row0 + w * 16 + l4 * 4 + reg;
    bool ok = gr < N_NODES;
    float s = 0.f, dd = 0.f;
#pragma unroll
    for (int cf = 0; cf < 4; cf++) {
      float v = acc[cf][reg];
      if (ok) h2b[(size_t)gr * HID + cf * 16 + l15] = f2bf(v);
      s += v * as_c[cf];
      dd += v * ad_c[cf];
    }
#pragma unroll
    for (int m = 1; m <= 8; m <<= 1) { s += __shfl_xor(s, m, 64); dd += __shfl_xor(dd, m, 64); }
    if (ok && l15 == 0) { aS[gr] = s; aD[gr] = dd; }
  }
}

// ---------------- layer-2 aggregate + fused pooling + fused final classifier (last block) ----------------
__global__ void __launch_bounds__(256) k_agg2(const int* __restrict__ row_ptr, const int* __restrict__ col,
                                              const float* __restrict__ aS, const float* __restrict__ aD,
                                              const unsigned short* __restrict__ h2b, const float* __restrict__ b2,
                                              const float* __restrict__ g2, const float* __restrict__ be2,
                                              const float* __restrict__ m2, const float* __restrict__ v2,
                                              const int* __restrict__ rootp, float* __restrict__ psum,
                                              unsigned int* __restrict__ pmaxenc, float* __restrict__ root_emb,
                                              const float* __restrict__ cg1w, const float* __restrict__ cg1b,
                                              const float* __restrict__ cbng, const float* __restrict__ cbnb,
                                              const float* __restrict__ cbnm, const float* __restrict__ cbnv,
                                              const float* __restrict__ cg2w, const float* __restrict__ cg2b,
                                              const float* __restrict__ cg3w, const float* __restrict__ cg3b,
                                              unsigned int* __restrict__ ctr, float* __restrict__ out) {
  __shared__ float ss[4][64], sm[4][64];
  __shared__ float g[192], t1[64], t2[32];
  __shared__ unsigned int ticket;
  int wave = threadIdx.x >> 6;
  int lane = threadIdx.x & 63;
  int d = blockIdx.x * 4 + wave;          // N_NODES == 25000*4 exactly
  float ad = aD[d];
  int s0 = row_ptr[d], s1 = row_ptr[d + 1];
  int s1m1 = s1 - 1;
  float denom = 0.f, acc = 0.f;
  for (int base = s0; base < s1; base += 8) {
    int left = s1 - base;                       // wave-uniform
    int idx = base + (lane & 7); if (idx > s1m1) idx = s1m1;
    int cv = col[idx];
    int sid[8];
#pragma unroll
    for (int j = 0; j < 8; j++) sid[j] = __builtin_amdgcn_readfirstlane(__shfl(cv, j));
    float e[8];
#pragma unroll
    for (int j = 0; j < 8; j++) e[j] = aS[sid[j]];          // scalar loads, L2-resident
    unsigned short h[8];
#pragma unroll
    for (int j = 0; j < 8; j++) h[j] = h2b[((size_t)sid[j] << 6) + lane];
    float wv[8];
#pragma unroll
    for (int j = 0; j < 8; j++) {
      float wl = __expf(fminf(leaky(e[j] + ad), 80.f));
      wv[j] = (j < left) ? wl : 0.f;            // uniform mask
    }
#pragma unroll
    for (int j = 0; j < 8; j++) {
      denom += wv[j];
      acc += wv[j] * bf2f(h[j]);
    }
  }
  float o = acc / (denom + 1e-16f) + b2[lane];
  o = (o - m2[lane]) * rsqrtf(v2[lane] + BN_EPS) * g2[lane] + be2[lane];
  o = elu_f(o);
  ss[wave][lane] = o;
  sm[wave][lane] = o;
  int root0 = rootp[0];
  if (root0 > N_NODES - 1) root0 = N_NODES - 1;
  if (root0 < 0) root0 = 0;
  if (d == root0)
    __hip_atomic_store(&root_emb[lane], o, __ATOMIC_RELEASE, __HIP_MEMORY_SCOPE_AGENT);
  __syncthreads();
  if (threadIdx.x < 64) {
    int c = threadIdx.x;
    float s4 = ss[0][c] + ss[1][c] + ss[2][c] + ss[3][c];
    float m4 = fmaxf(fmaxf(sm[0][c], sm[1][c]), fmaxf(sm[2][c], sm[3][c]));
    int slot = (blockIdx.x & 255) * 64 + c;
    atomicAdd(&psum[slot], s4);
    atomicMax(&pmaxenc[slot], encf(m4));
  }
  // last-finished block runs the classifier
  __threadfence();
  __syncthreads();
  if (threadIdx.x == 0) ticket = atomicAdd(&ctr[1], 1u);
  __syncthreads();
  if (ticket == (unsigned int)(gridDim.x - 1)) {
    int t = threadIdx.x;
    int c = t & 63, q = t >> 6;
    float s = 0.f, m = -INFINITY;
    for (int b = q; b < 256; b += 4) {
      s += __hip_atomic_load(&psum[b * 64 + c], __ATOMIC_ACQUIRE, __HIP_MEMORY_SCOPE_AGENT);
      unsigned int pe = __hip_atomic_load(&pmaxenc[b * 64 + c], __ATOMIC_ACQUIRE, __HIP_MEMORY_SCOPE_AGENT);
      m = fmaxf(m, decf(pe));
    }
    ss[q][c] = s; sm[q][c] = m;
    __syncthreads();
    if (t < 64) {
      float tot = ss[0][t] + ss[1][t] + ss[2][t] + ss[3][t];
      float mx = fmaxf(fmaxf(sm[0][t], sm[1][t]), fmaxf(sm[2][t], sm[3][t]));
      g[t] = tot / (float)N_NODES;
      g[64 + t] = mx;
      g[128 + t] = __hip_atomic_load(&root_emb[t], __ATOMIC_ACQUIRE, __HIP_MEMORY_SCOPE_AGENT);
    }
    __syncthreads();
    if (t < 64) {
      float o1 = cg1b[t];
      for (int i = 0; i < 192; i++) o1 += g[i] * cg1w[i * 64 + t];
      o1 = (o1 - cbnm[t]) * rsqrtf(cbnv[t] + BN_EPS) * cbng[t] + cbnb[t];
      t1[t] = o1 > 0.f ? o1 : 0.f;
    }
    __syncthreads();
    if (t < 32) {
      float o2 = cg2b[t];
      for (int i = 0; i < 64; i++) o2 += t1[i] * cg2w[i * 32 + t];
      t2[t] = o2 > 0.f ? o2 : 0.f;
    }
    __syncthreads();
    if (t == 0) {
      float o3 = cg3b[0];
      for (int i = 0; i < 32; i++) o3 += t2[i] * cg3w[i];
      out[0] = o3;
    }
  }
}

extern "C" void kernel_launch(void* const* d_in, const int* in_sizes, int n_in,
                              void* d_out, int out_size, void* d_ws, size_t ws_size,
                              hipStream_t stream) {
  const float* x     = (const float*)d_in[0];
  const int*   edge  = (const int*)d_in[1];
  const int*   root  = (const int*)d_in[2];
  const float* W1    = (const float*)d_in[3];
  const float* attS1 = (const float*)d_in[4];
  const float* attD1 = (const float*)d_in[5];
  const float* b1    = (const float*)d_in[6];
  const float* W2    = (const float*)d_in[7];
  const float* attS2 = (const float*)d_in[8];
  const float* attD2 = (const float*)d_in[9];
  const float* b2    = (const float*)d_in[10];
  const float* bn1g  = (const float*)d_in[11];
  const float* bn1b  = (const float*)d_in[12];
  const float* bn1m  = (const float*)d_in[13];
  const float* bn1v  = (const float*)d_in[14];
  const float* bn2g  = (const float*)d_in[15];
  const float* bn2b  = (const float*)d_in[16];
  const float* bn2m  = (const float*)d_in[17];
  const float* bn2v  = (const float*)d_in[18];
  const float* cg1w  = (const float*)d_in[19];
  const float* cg1b  = (const float*)d_in[20];
  const float* cbng  = (const float*)d_in[21];
  const float* cbnb  = (const float*)d_in[22];
  const float* cbnm  = (const float*)d_in[23];
  const float* cbnv  = (const float*)d_in[24];
  const float* cg2w  = (const float*)d_in[25];
  const float* cg2b  = (const float*)d_in[26];
  const float* cg3w  = (const float*)d_in[27];
  const float* cg3b  = (const float*)d_in[28];

  // workspace arena (256B aligned blocks)
  char* ws = (char*)d_ws;
  size_t off = 0;
  auto carve = [&](size_t bytes) { char* p = ws + off; off += (bytes + 255) & ~(size_t)255; return p; };
  unsigned short* h1b = (unsigned short*)carve((size_t)N_NODES * C1 * 2);  // 51.2 MB
  unsigned short* hmb = (unsigned short*)carve((size_t)N_NODES * C1 * 2);  // 51.2 MB
  float* w1      = (float*)carve((size_t)ETOT * 4 * 4);                    // 27.2 MB
  float* aS1     = (float*)carve((size_t)N_NODES * 4 * 4);
  float* aD1     = (float*)carve((size_t)N_NODES * 4 * 4);
  int*   deg     = (int*)  carve((size_t)N_NODES * 4);
  int*   row_ptr = (int*)  carve((size_t)(N_NODES + 1) * 4);
  int*   cursor  = (int*)  carve((size_t)N_NODES * 4);
  int*   col     = (int*)  carve((size_t)ETOT * 4);
  int*   part    = (int*)  carve(512);
  unsigned short* W1T = (unsigned short*)carve((size_t)IN_CH * C1 * 2);    // 64 KB
  unsigned short* W2T = (unsigned short*)carve((size_t)C1 * HID * 2);      // 32 KB
  float* psum    = (float*)carve(256 * 64 * 4);
  unsigned int* pmaxenc = (unsigned int*)carve(256 * 64 * 4);
  float* root_emb = (float*)carve(64 * 4);
  unsigned int* ctr = (unsigned int*)carve(32);
  // aliases into dead regions:
  unsigned short* h2b = h1b;                           // h1b dead after k_agg1
  float* aS2  = (float*)(h1b + (size_t)N_NODES * HID); // N floats
  float* aD2  = aS2 + N_NODES;

  int bpp_deg  = (N_EDGES + 1023) >> 10;
  int bpp_fill = (ETOT + 255) >> 8;
  // init (deg=1, W transposes, pool partials, ctrs) + degree + GEMM1
  k_prep_init<<<(N_NODES + 255) / 256, 256, 0, stream>>>(W1, W2, W1T, W2T, deg, psum, pmaxenc, ctr);
  k_deg_ph<<<bpp_deg * DEG_PH, 256, 0, stream>>>(edge, deg);
  k_gemm1<<<(N_NODES + 63) / 64, 256, 0, stream>>>(x, W1T, attS1, attD1, h1b, aS1, aD1);
  k_scan_part_top<<<NCHUNK, 256, 0, stream>>>(deg, part, row_ptr, ctr);
  k_scan_down<<<NCHUNK, 256, 0, stream>>>(deg, part, row_ptr, cursor);
  k_fill_ph<<<bpp_fill * FILL_PH, 256, 0, stream>>>(edge, cursor, aS1, aD1, col, w1);
  // layer 1 aggregate
  k_agg1<<<(N_NODES + 3) / 4, 256, 0, stream>>>(row_ptr, col, w1, h1b, b1, bn1g, bn1b, bn1m, bn1v, hmb);
  // layer 2 (+ pooling + classifier fused)
  k_gemm2<<<(N_NODES + 63) / 64, 256, 0, stream>>>(hmb, W2T, attS2, attD2, h2b, aS2, aD2);
  k_agg2<<<N_NODES / 4, 256, 0, stream>>>(row_ptr, col, aS2, aD2, h2b, b2, bn2g, bn2b, bn2m, bn2v,
                                          root, psum, pmaxenc, root_emb,
                                          cg1w, cg1b, cbng, cbnb, cbnm, cbnv,
                                          cg2w, cg2b, cg3w, cg3b, ctr, (float*)d_out);
}

// Round 14
// 477.898 us; speedup vs baseline: 5.2587x; 5.2587x over previous
//
#include <hip/hip_runtime.h>

#define N_NODES 100000
#define N_EDGES 1600000
#define ETOT    1700000   // edges + self loops
#define IN_CH   128
#define C1      256       // HEADS*HID
#define HID     64
#define BN_EPS  1e-5f
#define SLOPE   0.2f
#define NCHUNK  98        // ceil(N/1024)
#define DEG_PH  8
#define DEG_PHN 12500     // N_NODES / DEG_PH
#define FILL_PH 12
#define FILL_PHN 8334     // ceil(N_NODES / FILL_PH)

typedef __attribute__((ext_vector_type(8))) short s16x8;
typedef __attribute__((ext_vector_type(4))) float f32x4;
#define MFMA16(a, b, c) __builtin_amdgcn_mfma_f32_16x16x32_bf16(a, b, c, 0, 0, 0)

__device__ __forceinline__ float leaky(float x) { return fmaxf(x, SLOPE * x); }
__device__ __forceinline__ float elu_f(float x) { return x > 0.f ? x : __expf(x) - 1.f; }
__device__ __forceinline__ unsigned short f2bf(float f) {   // RNE fp32->bf16
  unsigned int b = __float_as_uint(f);
  return (unsigned short)((b + 0x7FFFu + ((b >> 16) & 1u)) >> 16);
}
__device__ __forceinline__ float bf2f(unsigned short u) {
  return __uint_as_float((unsigned int)u << 16);
}
// monotone float<->uint encode for atomicMax on possibly-negative floats
__device__ __forceinline__ unsigned int encf(float f) {
  unsigned int b = __float_as_uint(f);
  return b ^ ((((int)b >> 31)) | 0x80000000u);
}
__device__ __forceinline__ float decf(unsigned int k) {
  unsigned int b = (k & 0x80000000u) ? (k ^ 0x80000000u) : ~k;
  return __uint_as_float(b);
}

// ---------------- combined init: weights transpose + deg=1 + pool partials ----------------
__global__ void __launch_bounds__(256) k_prep_init(const float* __restrict__ W1, const float* __restrict__ W2,
                                                   unsigned short* __restrict__ W1T, unsigned short* __restrict__ W2T,
                                                   int* __restrict__ deg, float* __restrict__ psum,
                                                   unsigned int* __restrict__ pmaxenc) {
  int i = blockIdx.x * 256 + threadIdx.x;
  if (i < N_NODES) deg[i] = 1;  // self loop
  if (i < IN_CH * C1) {
    int k = i >> 8, c = i & 255;
    W1T[c * IN_CH + k] = f2bf(W1[i]);
  }
  if (i < C1 * HID) {
    int k = i >> 6, c = i & 63;
    W2T[c * C1 + k] = f2bf(W2[i]);
  }
  if (i < 256 * 64) { psum[i] = 0.f; pmaxenc[i] = 0u; }
}

// dst-range phased degree count: confine atomic targets to 50KB (L2-resident).
__global__ void __launch_bounds__(256) k_deg_ph(const int* __restrict__ edge, int* __restrict__ deg) {
  int bpp = (N_EDGES + 1023) >> 10;      // blocks per phase, 4 edges/thread
  int ph = blockIdx.x / bpp;
  int lo = ph * DEG_PHN, hi = lo + DEG_PHN;
  int i0 = (blockIdx.x % bpp) * 1024 + threadIdx.x * 4;
  if (i0 >= N_EDGES) return;
  if (i0 + 3 < N_EDGES) {
    int4 dv = *(const int4*)(edge + N_EDGES + i0);
    if (dv.x >= lo && dv.x < hi) atomicAdd(&deg[dv.x], 1);
    if (dv.y >= lo && dv.y < hi) atomicAdd(&deg[dv.y], 1);
    if (dv.z >= lo && dv.z < hi) atomicAdd(&deg[dv.z], 1);
    if (dv.w >= lo && dv.w < hi) atomicAdd(&deg[dv.w], 1);
  } else {
    for (int j = 0; j < 4 && i0 + j < N_EDGES; j++) {
      int d = edge[N_EDGES + i0 + j];
      if (d >= lo && d < hi) atomicAdd(&deg[d], 1);
    }
  }
}

__global__ void __launch_bounds__(256) k_scan_part(const int* __restrict__ deg, int* __restrict__ part) {
  __shared__ int ls[256];
  int t = threadIdx.x;
  int base = blockIdx.x * 1024 + t * 4;
  int s = 0;
#pragma unroll
  for (int j = 0; j < 4; j++) if (base + j < N_NODES) s += deg[base + j];
  ls[t] = s;
  __syncthreads();
  for (int off = 128; off >= 1; off >>= 1) {
    if (t < off) ls[t] += ls[t + off];
    __syncthreads();
  }
  if (t == 0) part[blockIdx.x] = ls[0];
}

__global__ void k_scan_top(int* __restrict__ part, int* __restrict__ row_ptr) {
  if (threadIdx.x == 0 && blockIdx.x == 0) {
    int run = 0;
    for (int i = 0; i < NCHUNK; i++) { int t = part[i]; part[i] = run; run += t; }
    row_ptr[N_NODES] = run;   // == ETOT
  }
}

__global__ void __launch_bounds__(256) k_scan_down(const int* __restrict__ deg, const int* __restrict__ part,
                                                   int* __restrict__ row_ptr, int* __restrict__ cursor) {
  __shared__ int ls[256];
  int t = threadIdx.x;
  int base = blockIdx.x * 1024 + t * 4;
  int v[4];
#pragma unroll
  for (int j = 0; j < 4; j++) v[j] = (base + j < N_NODES) ? deg[base + j] : 0;
  int tsum = v[0] + v[1] + v[2] + v[3];
  ls[t] = tsum;
  __syncthreads();
  for (int off = 1; off < 256; off <<= 1) {
    int add = (t >= off) ? ls[t - off] : 0;
    __syncthreads();
    ls[t] += add;
    __syncthreads();
  }
  int excl = ls[t] - tsum + part[blockIdx.x];
#pragma unroll
  for (int j = 0; j < 4; j++) {
    int idx = base + j;
    if (idx < N_NODES) { row_ptr[idx] = excl; cursor[idx] = excl; }
    excl += v[j];
  }
}

// dst-range phased fill + layer-1 edge-weight precompute.
// Scatter window per phase: col ~570KB + w1 ~2.3MB < 4MB per-XCD L2.
__global__ void __launch_bounds__(256) k_fill_ph(const int* __restrict__ edge, int* __restrict__ cursor,
                                                 const float* __restrict__ aS, const float* __restrict__ aD,
                                                 int* __restrict__ col, float* __restrict__ w1) {
  int bpp = (ETOT + 255) >> 8;           // blocks per phase
  int ph = blockIdx.x / bpp;
  int lo = ph * FILL_PHN, hi = lo + FILL_PHN;
  int i = (blockIdx.x % bpp) * 256 + threadIdx.x;
  if (i >= ETOT) return;
  int d = (i < N_EDGES) ? edge[N_EDGES + i] : (i - N_EDGES);
  if (d < lo || d >= hi) return;         // out-of-window lanes issue nothing below
  int s = (i < N_EDGES) ? edge[i] : d;
  int pos = atomicAdd(&cursor[d], 1);
  col[pos] = s;
  float4 as4 = *(const float4*)(aS + (size_t)s * 4);
  float4 ad4 = *(const float4*)(aD + (size_t)d * 4);
  float4 w;
  w.x = __expf(fminf(leaky(as4.x + ad4.x), 80.f));
  w.y = __expf(fminf(leaky(as4.y + ad4.y), 80.f));
  w.z = __expf(fminf(leaky(as4.z + ad4.z), 80.f));
  w.w = __expf(fminf(leaky(as4.w + ad4.w), 80.f));
  *(float4*)(w1 + (size_t)pos * 4) = w;
}

// ---------------- GEMM1 (MFMA bf16): h1 = x @ W1, fused att dots ----------------
__global__ void __launch_bounds__(256) k_gemm1(const float* __restrict__ x, const unsigned short* __restrict__ W1T,
                                               const float* __restrict__ attS, const float* __restrict__ attD,
                                               unsigned short* __restrict__ h1b, float* __restrict__ aS,
                                               float* __restrict__ aD) {
  __shared__ unsigned short As[64][IN_CH + 8];   // +8 pad -> <=2-way bank conflict on frag reads
  int tid = threadIdx.x;
  int w = tid >> 6, lane = tid & 63;
  int l15 = lane & 15, l4 = lane >> 4;
  int row0 = blockIdx.x * 64;
#pragma unroll
  for (int it = 0; it < 8; it++) {
    int idx = tid + it * 256;          // float4 chunk id, 2048 total
    int r = idx >> 5;
    int k4 = (idx & 31) * 4;
    int gr = row0 + r; if (gr >= N_NODES) gr = N_NODES - 1;
    float4 v = *(const float4*)(x + (size_t)gr * IN_CH + k4);
    ushort4 bvec;
    bvec.x = f2bf(v.x); bvec.y = f2bf(v.y); bvec.z = f2bf(v.z); bvec.w = f2bf(v.w);
    *(ushort4*)&As[r][k4] = bvec;
  }
  __syncthreads();
  f32x4 acc[4][4];                     // [mf][cf]
#pragma unroll
  for (int mf = 0; mf < 4; mf++)
#pragma unroll
    for (int cf = 0; cf < 4; cf++) acc[mf][cf] = (f32x4){0.f, 0.f, 0.f, 0.f};
#pragma unroll
  for (int ks = 0; ks < 4; ks++) {
    int koff = ks * 32 + l4 * 8;
    s16x8 a[4];
#pragma unroll
    for (int mf = 0; mf < 4; mf++) a[mf] = *(const s16x8*)&As[mf * 16 + l15][koff];
#pragma unroll
    for (int cf = 0; cf < 4; cf++) {
      s16x8 b = *(const s16x8*)(W1T + (size_t)(w * 64 + cf * 16 + l15) * IN_CH + koff);
#pragma unroll
      for (int mf = 0; mf < 4; mf++) acc[mf][cf] = MFMA16(a[mf], b, acc[mf][cf]);
    }
  }
  float as_c[4], ad_c[4];
#pragma unroll
  for (int cf = 0; cf < 4; cf++) {
    as_c[cf] = attS[w * HID + cf * 16 + l15];
    ad_c[cf] = attD[w * HID + cf * 16 + l15];
  }
#pragma unroll
  for (int mf = 0; mf < 4; mf++) {
#pragma unroll
    for (int reg = 0; reg < 4; reg++) {
      int gr = row0 + mf * 16 + l4 * 4 + reg;
      bool ok = gr < N_NODES;
      float s = 0.f, dd = 0.f;
#pragma unroll
      for (int cf = 0; cf < 4; cf++) {
        float v = acc[mf][cf][reg];
        if (ok) h1b[(size_t)gr * C1 + w * 64 + cf * 16 + l15] = f2bf(v);
        s += v * as_c[cf];
        dd += v * ad_c[cf];
      }
#pragma unroll
      for (int m = 1; m <= 8; m <<= 1) { s += __shfl_xor(s, m, 64); dd += __shfl_xor(dd, m, 64); }
      if (ok && l15 == 0) {
        aS[(size_t)gr * 4 + w] = s;
        aD[(size_t)gr * 4 + w] = dd;
      }
    }
  }
}

// ---------------- layer-1 aggregate: precomputed weights, masked-tail 8-deep pipeline ----------------
__global__ void __launch_bounds__(256) k_agg1(const int* __restrict__ row_ptr, const int* __restrict__ col,
                                              const float* __restrict__ w1,
                                              const unsigned short* __restrict__ h1b, const float* __restrict__ b1,
                                              const float* __restrict__ g1, const float* __restrict__ be1,
                                              const float* __restrict__ m1, const float* __restrict__ v1,
                                              unsigned short* __restrict__ hmb) {
  int wave = threadIdx.x >> 6;
  int lane = threadIdx.x & 63;
  int d = blockIdx.x * 4 + wave;
  if (d >= N_NODES) return;
  int head = lane >> 4;
  int s0 = row_ptr[d], s1 = row_ptr[d + 1];
  int s1m1 = s1 - 1;
  float denom = 0.f;
  float4 acc = {0.f, 0.f, 0.f, 0.f};
  int c0 = lane * 4;
  for (int base = s0; base < s1; base += 8) {
    int left = s1 - base;                       // wave-uniform
    int idx = base + (lane & 7); if (idx > s1m1) idx = s1m1;
    int cv = col[idx];
    int sid[8];
#pragma unroll
    for (int j = 0; j < 8; j++) sid[j] = __builtin_amdgcn_readfirstlane(__shfl(cv, j));
    float wv[8];
#pragma unroll
    for (int j = 0; j < 8; j++) {
      int wi = base + j; if (wi > s1m1) wi = s1m1;
      float wl = w1[(size_t)wi * 4 + head];
      wv[j] = (j < left) ? wl : 0.f;            // uniform mask -> cndmask, no divergence
    }
    ushort4 h[8];
#pragma unroll
    for (int j = 0; j < 8; j++) h[j] = *(const ushort4*)(h1b + ((size_t)sid[j] << 8) + c0);
#pragma unroll
    for (int j = 0; j < 8; j++) {
      denom += wv[j];
      acc.x += wv[j] * bf2f(h[j].x);
      acc.y += wv[j] * bf2f(h[j].y);
      acc.z += wv[j] * bf2f(h[j].z);
      acc.w += wv[j] * bf2f(h[j].w);
    }
  }
  float inv = 1.f / (denom + 1e-16f);
  float4 bb = *(const float4*)(b1 + c0);
  float4 gg = *(const float4*)(g1 + c0);
  float4 be = *(const float4*)(be1 + c0);
  float4 mm = *(const float4*)(m1 + c0);
  float4 vv = *(const float4*)(v1 + c0);
  ushort4 o;
  o.x = f2bf(elu_f((acc.x * inv + bb.x - mm.x) * rsqrtf(vv.x + BN_EPS) * gg.x + be.x));
  o.y = f2bf(elu_f((acc.y * inv + bb.y - mm.y) * rsqrtf(vv.y + BN_EPS) * gg.y + be.y));
  o.z = f2bf(elu_f((acc.z * inv + bb.z - mm.z) * rsqrtf(vv.z + BN_EPS) * gg.z + be.z));
  o.w = f2bf(elu_f((acc.w * inv + bb.w - mm.w) * rsqrtf(vv.w + BN_EPS) * gg.w + be.w));
  *(ushort4*)(hmb + (size_t)d * C1 + c0) = o;
}

// ---------------- GEMM2 (MFMA bf16): h2 = hm @ W2, fused att dots ----------------
__global__ void __launch_bounds__(256) k_gemm2(const unsigned short* __restrict__ hmb, const unsigned short* __restrict__ W2T,
                                               const float* __restrict__ attS, const float* __restrict__ attD,
                                               unsigned short* __restrict__ h2b, float* __restrict__ aS,
                                               float* __restrict__ aD) {
  __shared__ unsigned short As[64][C1 + 8];     // 33.8 KB
  int tid = threadIdx.x;
  int w = tid >> 6, lane = tid & 63;
  int l15 = lane & 15, l4 = lane >> 4;
  int row0 = blockIdx.x * 64;
#pragma unroll
  for (int it = 0; it < 8; it++) {
    int idx = tid + it * 256;          // uint4 chunk (8 bf16), 2048 total
    int r = idx >> 5;
    int k8 = (idx & 31) * 8;
    int gr = row0 + r; if (gr >= N_NODES) gr = N_NODES - 1;
    *(uint4*)&As[r][k8] = *(const uint4*)(hmb + (size_t)gr * C1 + k8);
  }
  __syncthreads();
  f32x4 acc[4];                        // [cf]
#pragma unroll
  for (int cf = 0; cf < 4; cf++) acc[cf] = (f32x4){0.f, 0.f, 0.f, 0.f};
#pragma unroll
  for (int ks = 0; ks < 8; ks++) {
    int koff = ks * 32 + l4 * 8;
    s16x8 a = *(const s16x8*)&As[w * 16 + l15][koff];
#pragma unroll
    for (int cf = 0; cf < 4; cf++) {
      s16x8 b = *(const s16x8*)(W2T + (size_t)(cf * 16 + l15) * C1 + koff);
      acc[cf] = MFMA16(a, b, acc[cf]);
    }
  }
  float as_c[4], ad_c[4];
#pragma unroll
  for (int cf = 0; cf < 4; cf++) {
    as_c[cf] = attS[cf * 16 + l15];
    ad_c[cf] = attD[cf * 16 + l15];
  }
#pragma unroll
  for (int reg = 0; reg < 4; reg++) {
    int gr = row0 + w * 16 + l4 * 4 + reg;
    bool ok = gr < N_NODES;
    float s = 0.f, dd = 0.f;
#pragma unroll
    for (int cf = 0; cf < 4; cf++) {
      float v = acc[cf][reg];
      if (ok) h2b[(size_t)gr * HID + cf * 16 + l15] = f2bf(v);
      s += v * as_c[cf];
      dd += v * ad_c[cf];
    }
#pragma unroll
    for (int m = 1; m <= 8; m <<= 1) { s += __shfl_xor(s, m, 64); dd += __shfl_xor(dd, m, 64); }
    if (ok && l15 == 0) { aS[gr] = s; aD[gr] = dd; }
  }
}

// ---------------- layer-2 aggregate + fused pooling (mean/max/root), 8-deep masked ----------------
__global__ void __launch_bounds__(256) k_agg2(const int* __restrict__ row_ptr, const int* __restrict__ col,
                                              const float* __restrict__ aS, const float* __restrict__ aD,
                                              const unsigned short* __restrict__ h2b, const float* __restrict__ b2,
                                              const float* __restrict__ g2, const float* __restrict__ be2,
                                              const float* __restrict__ m2, const float* __restrict__ v2,
                                              const int* __restrict__ rootp, float* __restrict__ psum,
                                              unsigned int* __restrict__ pmaxenc, float* __restrict__ root_emb) {
  __shared__ float ss[4][64], sm[4][64];
  int wave = threadIdx.x >> 6;
  int lane = threadIdx.x & 63;
  int d = blockIdx.x * 4 + wave;          // N_NODES == 25000*4 exactly
  float ad = aD[d];
  int s0 = row_ptr[d], s1 = row_ptr[d + 1];
  int s1m1 = s1 - 1;
  float denom = 0.f, acc = 0.f;
  for (int base = s0; base < s1; base += 8) {
    int left = s1 - base;                       // wave-uniform
    int idx = base + (lane & 7); if (idx > s1m1) idx = s1m1;
    int cv = col[idx];
    int sid[8];
#pragma unroll
    for (int j = 0; j < 8; j++) sid[j] = __builtin_amdgcn_readfirstlane(__shfl(cv, j));
    float e[8];
#pragma unroll
    for (int j = 0; j < 8; j++) e[j] = aS[sid[j]];          // scalar loads, L2-resident
    unsigned short h[8];
#pragma unroll
    for (int j = 0; j < 8; j++) h[j] = h2b[((size_t)sid[j] << 6) + lane];
    float wv[8];
#pragma unroll
    for (int j = 0; j < 8; j++) {
      float wl = __expf(fminf(leaky(e[j] + ad), 80.f));
      wv[j] = (j < left) ? wl : 0.f;            // uniform mask
    }
#pragma unroll
    for (int j = 0; j < 8; j++) {
      denom += wv[j];
      acc += wv[j] * bf2f(h[j]);
    }
  }
  float o = acc / (denom + 1e-16f) + b2[lane];
  o = (o - m2[lane]) * rsqrtf(v2[lane] + BN_EPS) * g2[lane] + be2[lane];
  o = elu_f(o);
  ss[wave][lane] = o;
  sm[wave][lane] = o;
  int root0 = rootp[0];
  if (root0 > N_NODES - 1) root0 = N_NODES - 1;
  if (root0 < 0) root0 = 0;
  if (d == root0) root_emb[lane] = o;
  __syncthreads();
  if (threadIdx.x < 64) {
    int c = threadIdx.x;
    float s4 = ss[0][c] + ss[1][c] + ss[2][c] + ss[3][c];
    float m4 = fmaxf(fmaxf(sm[0][c], sm[1][c]), fmaxf(sm[2][c], sm[3][c]));
    int slot = (blockIdx.x & 255) * 64 + c;
    atomicAdd(&psum[slot], s4);
    atomicMax(&pmaxenc[slot], encf(m4));
  }
}

// ---------------- final reduce + classifier ----------------
__global__ void __launch_bounds__(256) k_final(const float* __restrict__ psum, const unsigned int* __restrict__ pmaxenc,
                                               const float* __restrict__ root_emb,
                                               const float* __restrict__ cg1w, const float* __restrict__ cg1b,
                                               const float* __restrict__ cbng, const float* __restrict__ cbnb,
                                               const float* __restrict__ cbnm, const float* __restrict__ cbnv,
                                               const float* __restrict__ cg2w, const float* __restrict__ cg2b,
                                               const float* __restrict__ cg3w, const float* __restrict__ cg3b,
                                               float* __restrict__ out) {
  __shared__ float ss[4][64], sm[4][64];
  __shared__ float g[192], t1[64], t2[32];
  int t = threadIdx.x;
  int c = t & 63, q = t >> 6;
  float s = 0.f, m = -INFINITY;
  for (int b = q; b < 256; b += 4) {
    s += psum[b * 64 + c];
    m = fmaxf(m, decf(pmaxenc[b * 64 + c]));
  }
  ss[q][c] = s; sm[q][c] = m;
  __syncthreads();
  if (t < 64) {
    float tot = ss[0][t] + ss[1][t] + ss[2][t] + ss[3][t];
    float mx = fmaxf(fmaxf(sm[0][t], sm[1][t]), fmaxf(sm[2][t], sm[3][t]));
    g[t] = tot / (float)N_NODES;
    g[64 + t] = mx;
    g[128 + t] = root_emb[t];
  }
  __syncthreads();
  if (t < 64) {
    float o = cg1b[t];
    for (int i = 0; i < 192; i++) o += g[i] * cg1w[i * 64 + t];
    o = (o - cbnm[t]) * rsqrtf(cbnv[t] + BN_EPS) * cbng[t] + cbnb[t];
    t1[t] = o > 0.f ? o : 0.f;
  }
  __syncthreads();
  if (t < 32) {
    float o = cg2b[t];
    for (int i = 0; i < 64; i++) o += t1[i] * cg2w[i * 32 + t];
    t2[t] = o > 0.f ? o : 0.f;
  }
  __syncthreads();
  if (t == 0) {
    float o = cg3b[0];
    for (int i = 0; i < 32; i++) o += t2[i] * cg3w[i];
    out[0] = o;
  }
}

extern "C" void kernel_launch(void* const* d_in, const int* in_sizes, int n_in,
                              void* d_out, int out_size, void* d_ws, size_t ws_size,
                              hipStream_t stream) {
  const float* x     = (const float*)d_in[0];
  const int*   edge  = (const int*)d_in[1];
  const int*   root  = (const int*)d_in[2];
  const float* W1    = (const float*)d_in[3];
  const float* attS1 = (const float*)d_in[4];
  const float* attD1 = (const float*)d_in[5];
  const float* b1    = (const float*)d_in[6];
  const float* W2    = (const float*)d_in[7];
  const float* attS2 = (const float*)d_in[8];
  const float* attD2 = (const float*)d_in[9];
  const float* b2    = (const float*)d_in[10];
  const float* bn1g  = (const float*)d_in[11];
  const float* bn1b  = (const float*)d_in[12];
  const float* bn1m  = (const float*)d_in[13];
  const float* bn1v  = (const float*)d_in[14];
  const float* bn2g  = (const float*)d_in[15];
  const float* bn2b  = (const float*)d_in[16];
  const float* bn2m  = (const float*)d_in[17];
  const float* bn2v  = (const float*)d_in[18];
  const float* cg1w  = (const float*)d_in[19];
  const float* cg1b  = (const float*)d_in[20];
  const float* cbng  = (const float*)d_in[21];
  const float* cbnb  = (const float*)d_in[22];
  const float* cbnm  = (const float*)d_in[23];
  const float* cbnv  = (const float*)d_in[24];
  const float* cg2w  = (const float*)d_in[25];
  const float* cg2b  = (const float*)d_in[26];
  const float* cg3w  = (const float*)d_in[27];
  const float* cg3b  = (const float*)d_in[28];

  // workspace arena (256B aligned blocks)
  char* ws = (char*)d_ws;
  size_t off = 0;
  auto carve = [&](size_t bytes) { char* p = ws + off; off += (bytes + 255) & ~(size_t)255; return p; };
  unsigned short* h1b = (unsigned short*)carve((size_t)N_NODES * C1 * 2);  // 51.2 MB
  unsigned short* hmb = (unsigned short*)carve((size_t)N_NODES * C1 * 2);  // 51.2 MB
  float* w1      = (float*)carve((size_t)ETOT * 4 * 4);                    // 27.2 MB
  float* aS1     = (float*)carve((size_t)N_NODES * 4 * 4);
  float* aD1     = (float*)carve((size_t)N_NODES * 4 * 4);
  int*   deg     = (int*)  carve((size_t)N_NODES * 4);
  int*   row_ptr = (int*)  carve((size_t)(N_NODES + 1) * 4);
  int*   cursor  = (int*)  carve((size_t)N_NODES * 4);
  int*   col     = (int*)  carve((size_t)ETOT * 4);
  int*   part    = (int*)  carve(512);
  unsigned short* W1T = (unsigned short*)carve((size_t)IN_CH * C1 * 2);    // 64 KB
  unsigned short* W2T = (unsigned short*)carve((size_t)C1 * HID * 2);      // 32 KB
  float* psum    = (float*)carve(256 * 64 * 4);
  unsigned int* pmaxenc = (unsigned int*)carve(256 * 64 * 4);
  float* root_emb = (float*)carve(64 * 4);
  // aliases into dead regions:
  unsigned short* h2b = h1b;                           // h1b dead after k_agg1
  float* aS2  = (float*)(h1b + (size_t)N_NODES * HID); // N floats
  float* aD2  = aS2 + N_NODES;

  int bpp_deg  = (N_EDGES + 1023) >> 10;
  int bpp_fill = (ETOT + 255) >> 8;
  // init (deg=1, W transposes, pool partials) + degree + GEMM1
  k_prep_init<<<(N_NODES + 255) / 256, 256, 0, stream>>>(W1, W2, W1T, W2T, deg, psum, pmaxenc);
  k_deg_ph<<<bpp_deg * DEG_PH, 256, 0, stream>>>(edge, deg);
  k_gemm1<<<(N_NODES + 63) / 64, 256, 0, stream>>>(x, W1T, attS1, attD1, h1b, aS1, aD1);
  k_scan_part<<<NCHUNK, 256, 0, stream>>>(deg, part);
  k_scan_top<<<1, 64, 0, stream>>>(part, row_ptr);
  k_scan_down<<<NCHUNK, 256, 0, stream>>>(deg, part, row_ptr, cursor);
  k_fill_ph<<<bpp_fill * FILL_PH, 256, 0, stream>>>(edge, cursor, aS1, aD1, col, w1);
  // layer 1 aggregate
  k_agg1<<<(N_NODES + 3) / 4, 256, 0, stream>>>(row_ptr, col, w1, h1b, b1, bn1g, bn1b, bn1m, bn1v, hmb);
  // layer 2
  k_gemm2<<<(N_NODES + 63) / 64, 256, 0, stream>>>(hmb, W2T, attS2, attD2, h2b, aS2, aD2);
  k_agg2<<<N_NODES / 4, 256, 0, stream>>>(row_ptr, col, aS2, aD2, h2b, b2, bn2g, bn2b, bn2m, bn2v,
                                          root, psum, pmaxenc, root_emb);
  k_final<<<1, 256, 0, stream>>>(psum, pmaxenc, root_emb, cg1w, cg1b, cbng, cbnb, cbnm, cbnv,
                                 cg2w, cg2b, cg3w, cg3b, (float*)d_out);
}